// Round 7
// baseline (224.650 us; speedup 1.0000x reference)
//
#include <hip/hip_runtime.h>
#include <hip/hip_bf16.h>

// Problem constants (B=8192, D=512 from reference setup_inputs)
#define BN_ 8192
#define DK_ 512
#define TEMP_INV 14.2857142857142857f   // 1/0.07
#define LOG2E_ 1.44269504088896f
#define MAXOFF 15.0f                    // fixed lse offset; |sim| < 14.29 (unit vectors)

typedef __bf16 bf16x8 __attribute__((ext_vector_type(8)));
typedef float f32x4 __attribute__((ext_vector_type(4)));

__device__ inline unsigned short f2bf(float f) {
    unsigned u = __float_as_uint(f);
    return (unsigned short)((u + 0x7FFFu + ((u >> 16) & 1u)) >> 16);
}

// ---------------- Kernel 1: L2-normalize rows, write bf16 ----------------
__global__ __launch_bounds__(256) void norm_kernel(const float* __restrict__ emb,
                                                   unsigned short* __restrict__ ebf) {
    const int row  = blockIdx.x * 4 + (threadIdx.x >> 6);
    const int lane = threadIdx.x & 63;
    const float4* src = reinterpret_cast<const float4*>(emb + (size_t)row * DK_);
    float4 v0 = src[lane];
    float4 v1 = src[lane + 64];
    float ss = v0.x*v0.x + v0.y*v0.y + v0.z*v0.z + v0.w*v0.w
             + v1.x*v1.x + v1.y*v1.y + v1.z*v1.z + v1.w*v1.w;
#pragma unroll
    for (int off = 1; off < 64; off <<= 1) ss += __shfl_xor(ss, off, 64);
    const float scale = 1.0f / fmaxf(sqrtf(ss), 1e-12f);
    uint2 o0, o1;
    o0.x = (unsigned)f2bf(v0.x * scale) | ((unsigned)f2bf(v0.y * scale) << 16);
    o0.y = (unsigned)f2bf(v0.z * scale) | ((unsigned)f2bf(v0.w * scale) << 16);
    o1.x = (unsigned)f2bf(v1.x * scale) | ((unsigned)f2bf(v1.y * scale) << 16);
    o1.y = (unsigned)f2bf(v1.z * scale) | ((unsigned)f2bf(v1.w * scale) << 16);
    uint2* dst = reinterpret_cast<uint2*>(ebf + (size_t)row * DK_);
    dst[lane]      = o0;
    dst[lane + 64] = o1;
}

// ---------------- Kernel 2: symmetric triangular tiles (cb >= rb) ----------------
// r6 structure + triangular: off-diag tiles credit rb-rows (row sums) AND cb-rows
// (col sums via symmetry). Mask patches for BOTH orientations stream through the
// staging phase (drained by the same vmcnt(0)+barrier as ebf, packed under MFMA).
// SWAPPED mfma operands (verified r5/r6): a = acc[fm][fn][rg] is sim(i,j) with
//   i = rb*128 + wr*64 + fm*16 + (lane&15)
//   j = cb*128 + wc*64 + fn*16 + (lane>>4)*4 + rg
__global__ __launch_bounds__(256) void infonce_main(
    const unsigned short* __restrict__ ebf,
    const int* __restrict__ mask,
    float* __restrict__ se, float* __restrict__ ps, float* __restrict__ ct) {

    __shared__ unsigned short As[128 * 64];       // 16KB
    __shared__ unsigned short Bs[128 * 64];       // 16KB
    __shared__ unsigned char  pmB [128 * 16];     // 2KB bits mask[rb-rows][cb-cols]
    __shared__ unsigned char  pmBT[128 * 16];     // 2KB bits mask[cb-rows][rb-cols]
    __shared__ float redR[2][128];                // rb-row partials {lse, pos}
    __shared__ float redC[2][128];                // cb-row partials {lse, pos}

    const int t    = threadIdx.x;
    const int lane = t & 63;
    const int wid  = t >> 6;
    const int wr   = wid >> 1;
    const int wc   = wid & 1;

    // triangular decode (verified r4): base(r) = 64r - r(r-1)/2
    const int bid = blockIdx.x;
    int rb = (int)((129.0f - sqrtf(16641.0f - 8.0f * (float)bid)) * 0.5f);
    while (64 * (rb + 1) - ((rb + 1) * rb) / 2 <= bid) ++rb;
    while (64 * rb - (rb * (rb - 1)) / 2 > bid) --rb;
    const int cb = rb + (bid - (64 * rb - (rb * (rb - 1)) / 2));
    const bool offd = (rb != cb);
    const bool db   = !offd;

    if (t < 128) { redR[0][t] = 0.f; redR[1][t] = 0.f; redC[0][t] = 0.f; redC[1][t] = 0.f; }

    f32x4 acc[4][4] = {};

    // ebf staging map: thread t -> row t/8 (of 32), 16B chunk (t%8) within 64-elem k-row
    const int sr = t >> 3;
    const int sc = (t & 7) * 8;
    const size_t arow0 = (size_t)(rb * 128 + sr) * DK_ + sc;
    const size_t brow0 = (size_t)(cb * 128 + sr) * DK_ + sc;

    // mask staging map: thread t -> patch row t>>4 (of 16 per kt), cols (t&15)*8..+7
    const int mr = t >> 4;
    const int mc = t & 15;
    const int* mbase  = mask + (size_t)(rb * 128 + mr) * BN_ + cb * 128 + mc * 8;
    const int* mbaseT = mask + (size_t)(cb * 128 + mr) * BN_ + rb * 128 + mc * 8;

    const int r16 = lane & 15;
    const int kg  = (lane >> 4) * 8;

#pragma unroll
    for (int kt = 0; kt < 8; ++kt) {
        const int k0 = kt * 64;
#pragma unroll
        for (int s = 0; s < 4; ++s) {
            __builtin_amdgcn_global_load_lds(
                (const __attribute__((address_space(1))) void*)(ebf + arow0 + (size_t)s * 32 * DK_ + k0),
                (__attribute__((address_space(3))) void*)(As + s * 2048 + t * 8),
                16, 0, 0);
        }
#pragma unroll
        for (int s = 0; s < 4; ++s) {
            __builtin_amdgcn_global_load_lds(
                (const __attribute__((address_space(1))) void*)(ebf + brow0 + (size_t)s * 32 * DK_ + k0),
                (__attribute__((address_space(3))) void*)(Bs + s * 2048 + t * 8),
                16, 0, 0);
        }
        // mask patches (coalesced int4, same vmcnt stream as the LDS staging)
        const int4* mp = reinterpret_cast<const int4*>(mbase + (size_t)kt * 16 * BN_);
        const int4 mv0 = mp[0];
        const int4 mv1 = mp[1];
        int4 tw0, tw1;
        if (offd) {   // block-uniform branch
            const int4* tp = reinterpret_cast<const int4*>(mbaseT + (size_t)kt * 16 * BN_);
            tw0 = tp[0];
            tw1 = tp[1];
        }

        __syncthreads();   // vmcnt(0) drain: LDS tiles + mask regs ready

        // pack bits -> tiles (overlaps MFMA phase)
        {
            unsigned by = (unsigned)(mv0.x != 0)        | ((unsigned)(mv0.y != 0) << 1)
                        | ((unsigned)(mv0.z != 0) << 2) | ((unsigned)(mv0.w != 0) << 3)
                        | ((unsigned)(mv1.x != 0) << 4) | ((unsigned)(mv1.y != 0) << 5)
                        | ((unsigned)(mv1.z != 0) << 6) | ((unsigned)(mv1.w != 0) << 7);
            pmB[(kt * 16 + mr) * 16 + mc] = (unsigned char)by;
            if (offd) {
                unsigned byT = (unsigned)(tw0.x != 0)        | ((unsigned)(tw0.y != 0) << 1)
                             | ((unsigned)(tw0.z != 0) << 2) | ((unsigned)(tw0.w != 0) << 3)
                             | ((unsigned)(tw1.x != 0) << 4) | ((unsigned)(tw1.y != 0) << 5)
                             | ((unsigned)(tw1.z != 0) << 6) | ((unsigned)(tw1.w != 0) << 7);
                pmBT[(kt * 16 + mr) * 16 + mc] = (unsigned char)byT;
            }
        }

#pragma unroll
        for (int ks = 0; ks < 2; ++ks) {
            bf16x8 af[4], bfr[4];
#pragma unroll
            for (int fm = 0; fm < 4; ++fm)
                af[fm] = *reinterpret_cast<const bf16x8*>(As + (wr * 64 + fm * 16 + r16) * 64 + ks * 32 + kg);
#pragma unroll
            for (int fn = 0; fn < 4; ++fn)
                bfr[fn] = *reinterpret_cast<const bf16x8*>(Bs + (wc * 64 + fn * 16 + r16) * 64 + ks * 32 + kg);
#pragma unroll
            for (int fm = 0; fm < 4; ++fm)
#pragma unroll
                for (int fn = 0; fn < 4; ++fn)
                    acc[fm][fn] = __builtin_amdgcn_mfma_f32_16x16x32_bf16(bfr[fn], af[fm], acc[fm][fn], 0, 0, 0);
        }
        __syncthreads();
    }

    // ---- epilogue ----
    const float C1 = TEMP_INV * LOG2E_;
    const float C2 = -MAXOFF * LOG2E_;
    const int l15 = lane & 15;
    const int g   = lane >> 4;
    const int gq4 = g * 4;

    // row mask words per fm (this wave's 64-col window selected by wc)
    uint2 rw[4];
#pragma unroll
    for (int fm = 0; fm < 4; ++fm) {
        const uint4 rv = *reinterpret_cast<const uint4*>(pmB + (wr * 64 + fm * 16 + l15) * 16);
        rw[fm].x = wc ? rv.z : rv.x;
        rw[fm].y = wc ? rv.w : rv.y;
    }
    float lseA[4] = {0.f, 0.f, 0.f, 0.f};
    float posA[4] = {0.f, 0.f, 0.f, 0.f};

#pragma unroll
    for (int fn = 0; fn < 4; ++fn) {
#pragma unroll
        for (int rg = 0; rg < 4; ++rg) {
            const int jl = wc * 64 + fn * 16 + gq4 + rg;   // local col / cb-row
            uint2 tv;
            if (offd) tv = *reinterpret_cast<const uint2*>(pmBT + jl * 16 + wr * 8);
            float colL = 0.f, colP = 0.f;
#pragma unroll
            for (int fm = 0; fm < 4; ++fm) {
                const float a = acc[fm][fn][rg];
                const bool dg = db && (wr == wc) && (fm == fn) && (l15 == gq4 + rg);
                const float ex = dg ? 0.0f : exp2f(fmaf(a, C1, C2));
                lseA[fm] += ex;
                const unsigned wsel = (fn < 2) ? rw[fm].x : rw[fm].y;
                const bool p = (((wsel >> ((fn & 1) * 16 + gq4 + rg)) & 1u) != 0u) && !dg;
                posA[fm] += p ? a : 0.0f;
                if (offd) {
                    colL += ex;   // symmetric credit: sim(j,i) == sim(i,j)
                    const unsigned cw = (fm < 2) ? tv.x : tv.y;
                    colP += ((cw >> ((fm & 1) * 16 + l15)) & 1u) ? a : 0.0f;
                }
            }
            if (offd) {
#pragma unroll
                for (int off = 1; off < 16; off <<= 1) {
                    colL += __shfl_xor(colL, off, 64);
                    colP += __shfl_xor(colP, off, 64);
                }
                if (l15 == 0) {
                    atomicAdd(&redC[0][jl], colL);
                    atomicAdd(&redC[1][jl], colP * TEMP_INV);
                }
            }
        }
    }
    // row-side: reduce over the 4 lane-groups (j spread over lane>>4)
#pragma unroll
    for (int fm = 0; fm < 4; ++fm) {
        float L = lseA[fm], P = posA[fm];
        L += __shfl_xor(L, 16, 64); L += __shfl_xor(L, 32, 64);
        P += __shfl_xor(P, 16, 64); P += __shfl_xor(P, 32, 64);
        if (g == 0) {
            const int li = wr * 64 + fm * 16 + l15;
            atomicAdd(&redR[0][li], L);
            atomicAdd(&redR[1][li], P * TEMP_INV);
        }
    }
    __syncthreads();
    if (t < 128) {
        const uint4 rv = *reinterpret_cast<const uint4*>(pmB + t * 16);
        float cnt = (float)(__popc(rv.x) + __popc(rv.y) + __popc(rv.z) + __popc(rv.w));
        if (db) {   // remove diagonal bit (diag col == local row t)
            const unsigned wsel = (t < 64) ? ((t < 32) ? rv.x : rv.y)
                                           : ((t < 96) ? rv.z : rv.w);
            cnt -= (float)((wsel >> (t & 31)) & 1u);
        }
        const int i = rb * 128 + t;
        atomicAdd(&se[i], redR[0][t]);
        atomicAdd(&ps[i], redR[1][t]);
        atomicAdd(&ct[i], cnt);
    } else if (offd) {
        const int r = t - 128;
        const uint4 tvr = *reinterpret_cast<const uint4*>(pmBT + r * 16);
        const float cnt = (float)(__popc(tvr.x) + __popc(tvr.y) + __popc(tvr.z) + __popc(tvr.w));
        const int j = cb * 128 + r;
        atomicAdd(&se[j], redC[0][r]);
        atomicAdd(&ps[j], redC[1][r]);
        atomicAdd(&ct[j], cnt);
    }
}

// ---------------- Kernel 3: finalize scalar loss (32 blocks) ----------------
__global__ __launch_bounds__(256) void finalize_kernel(const float* __restrict__ se,
                                                       const float* __restrict__ ps,
                                                       const float* __restrict__ ct,
                                                       float* __restrict__ out) {
    __shared__ float red[256];
    const int t = threadIdx.x;
    const int i = blockIdx.x * 256 + t;
    const float lse = logf(se[i]) + MAXOFF;
    red[t] = lse - ps[i] / fmaxf(ct[i], 1.0f);
    __syncthreads();
    for (int s = 128; s > 0; s >>= 1) {
        if (t < s) red[t] += red[t + s];
        __syncthreads();
    }
    if (t == 0) atomicAdd(out, red[0] * (1.0f / (float)BN_));
}

extern "C" void kernel_launch(void* const* d_in, const int* in_sizes, int n_in,
                              void* d_out, int out_size, void* d_ws, size_t ws_size,
                              hipStream_t stream) {
    const float* emb  = (const float*)d_in[0];
    const int*   mask = (const int*)d_in[1];
    float* out = (float*)d_out;

    char* ws = (char*)d_ws;
    unsigned short* ebf = (unsigned short*)ws;                  // 8 MB bf16 normalized
    float* se = (float*)(ws + (size_t)8 * 1024 * 1024);
    float* ps = se + BN_;
    float* ct = ps + BN_;

    hipMemsetAsync(se, 0, (size_t)3 * BN_ * sizeof(float), stream);
    hipMemsetAsync(out, 0, sizeof(float), stream);
    norm_kernel<<<BN_ / 4, 256, 0, stream>>>(emb, ebf);
    infonce_main<<<2080, 256, 0, stream>>>(ebf, mask, se, ps, ct);
    finalize_kernel<<<BN_ / 256, 256, 0, stream>>>(se, ps, ct, out);
}

// Round 8
// 183.357 us; speedup vs baseline: 1.2252x; 1.2252x over previous
//
#include <hip/hip_runtime.h>
#include <hip/hip_bf16.h>

// Problem constants (B=8192, D=512 from reference setup_inputs)
#define BN_ 8192
#define DK_ 512
#define TEMP_INV 14.2857142857142857f   // 1/0.07
#define LOG2E_ 1.44269504088896f
#define MAXOFF 15.0f                    // fixed lse offset; |sim| < 14.29 (unit vectors)

typedef __bf16 bf16x8 __attribute__((ext_vector_type(8)));
typedef float f32x4 __attribute__((ext_vector_type(4)));

__device__ inline unsigned short f2bf(float f) {
    unsigned u = __float_as_uint(f);
    return (unsigned short)((u + 0x7FFFu + ((u >> 16) & 1u)) >> 16);
}

// ---------------- Kernel 1: L2-normalize rows, write bf16 ----------------
__global__ __launch_bounds__(256) void norm_kernel(const float* __restrict__ emb,
                                                   unsigned short* __restrict__ ebf) {
    const int row  = blockIdx.x * 4 + (threadIdx.x >> 6);
    const int lane = threadIdx.x & 63;
    const float4* src = reinterpret_cast<const float4*>(emb + (size_t)row * DK_);
    float4 v0 = src[lane];
    float4 v1 = src[lane + 64];
    float ss = v0.x*v0.x + v0.y*v0.y + v0.z*v0.z + v0.w*v0.w
             + v1.x*v1.x + v1.y*v1.y + v1.z*v1.z + v1.w*v1.w;
#pragma unroll
    for (int off = 1; off < 64; off <<= 1) ss += __shfl_xor(ss, off, 64);
    const float scale = 1.0f / fmaxf(sqrtf(ss), 1e-12f);
    uint2 o0, o1;
    o0.x = (unsigned)f2bf(v0.x * scale) | ((unsigned)f2bf(v0.y * scale) << 16);
    o0.y = (unsigned)f2bf(v0.z * scale) | ((unsigned)f2bf(v0.w * scale) << 16);
    o1.x = (unsigned)f2bf(v1.x * scale) | ((unsigned)f2bf(v1.y * scale) << 16);
    o1.y = (unsigned)f2bf(v1.z * scale) | ((unsigned)f2bf(v1.w * scale) << 16);
    uint2* dst = reinterpret_cast<uint2*>(ebf + (size_t)row * DK_);
    dst[lane]      = o0;
    dst[lane + 64] = o1;
}

// ---------------- Kernel 2: symmetric triangular tiles (cb >= rb) ----------------
// r7 structure with two occupancy fixes:
//  (1) mask bits packed BEFORE the barrier (vmcnt drains there anyway) -> no
//      cross-barrier register liveness for mv/tw (saves ~16 VGPR);
//  (2) __launch_bounds__(256,4) pins VGPR <= 128 -> 4 blocks/CU (the 128 cliff).
// SWAPPED mfma operands (verified r5/r6): a = acc[fm][fn][rg] is sim(i,j) with
//   i = rb*128 + wr*64 + fm*16 + (lane&15)
//   j = cb*128 + wc*64 + fn*16 + (lane>>4)*4 + rg
__global__ __launch_bounds__(256, 4) void infonce_main(
    const unsigned short* __restrict__ ebf,
    const int* __restrict__ mask,
    float* __restrict__ se, float* __restrict__ ps, float* __restrict__ ct) {

    __shared__ unsigned short As[128 * 64];       // 16KB
    __shared__ unsigned short Bs[128 * 64];       // 16KB
    __shared__ unsigned char  pmB [128 * 16];     // 2KB bits mask[rb-rows][cb-cols]
    __shared__ unsigned char  pmBT[128 * 16];     // 2KB bits mask[cb-rows][rb-cols]
    __shared__ float redR[2][128];                // rb-row partials {lse, pos}
    __shared__ float redC[2][128];                // cb-row partials {lse, pos}

    const int t    = threadIdx.x;
    const int lane = t & 63;
    const int wid  = t >> 6;
    const int wr   = wid >> 1;
    const int wc   = wid & 1;

    // triangular decode (verified r4): base(r) = 64r - r(r-1)/2
    const int bid = blockIdx.x;
    int rb = (int)((129.0f - sqrtf(16641.0f - 8.0f * (float)bid)) * 0.5f);
    while (64 * (rb + 1) - ((rb + 1) * rb) / 2 <= bid) ++rb;
    while (64 * rb - (rb * (rb - 1)) / 2 > bid) --rb;
    const int cb = rb + (bid - (64 * rb - (rb * (rb - 1)) / 2));
    const bool offd = (rb != cb);
    const bool db   = !offd;

    if (t < 128) { redR[0][t] = 0.f; redR[1][t] = 0.f; redC[0][t] = 0.f; redC[1][t] = 0.f; }

    f32x4 acc[4][4] = {};

    // ebf staging map: thread t -> row t/8 (of 32), 16B chunk (t%8) within 64-elem k-row
    const int sr = t >> 3;
    const int sc = (t & 7) * 8;
    const size_t arow0 = (size_t)(rb * 128 + sr) * DK_ + sc;
    const size_t brow0 = (size_t)(cb * 128 + sr) * DK_ + sc;

    // mask staging map: thread t -> patch row t>>4 (of 16 per kt), cols (t&15)*8..+7
    const int mr = t >> 4;
    const int mc = t & 15;
    const int* mbase  = mask + (size_t)(rb * 128 + mr) * BN_ + cb * 128 + mc * 8;
    const int* mbaseT = mask + (size_t)(cb * 128 + mr) * BN_ + rb * 128 + mc * 8;

    const int r16 = lane & 15;
    const int kg  = (lane >> 4) * 8;

#pragma unroll
    for (int kt = 0; kt < 8; ++kt) {
        const int k0 = kt * 64;
#pragma unroll
        for (int s = 0; s < 4; ++s) {
            __builtin_amdgcn_global_load_lds(
                (const __attribute__((address_space(1))) void*)(ebf + arow0 + (size_t)s * 32 * DK_ + k0),
                (__attribute__((address_space(3))) void*)(As + s * 2048 + t * 8),
                16, 0, 0);
        }
#pragma unroll
        for (int s = 0; s < 4; ++s) {
            __builtin_amdgcn_global_load_lds(
                (const __attribute__((address_space(1))) void*)(ebf + brow0 + (size_t)s * 32 * DK_ + k0),
                (__attribute__((address_space(3))) void*)(Bs + s * 2048 + t * 8),
                16, 0, 0);
        }
        // mask patches (coalesced int4, same vmcnt stream as the LDS staging);
        // pack IMMEDIATELY (pre-barrier): the waitcnt lands where the barrier
        // would drain anyway, and mv/tw die before the barrier (VGPR slim).
        {
            const int4* mp = reinterpret_cast<const int4*>(mbase + (size_t)kt * 16 * BN_);
            const int4 mv0 = mp[0];
            const int4 mv1 = mp[1];
            unsigned by = (unsigned)(mv0.x != 0)        | ((unsigned)(mv0.y != 0) << 1)
                        | ((unsigned)(mv0.z != 0) << 2) | ((unsigned)(mv0.w != 0) << 3)
                        | ((unsigned)(mv1.x != 0) << 4) | ((unsigned)(mv1.y != 0) << 5)
                        | ((unsigned)(mv1.z != 0) << 6) | ((unsigned)(mv1.w != 0) << 7);
            pmB[(kt * 16 + mr) * 16 + mc] = (unsigned char)by;
            if (offd) {
                const int4* tp = reinterpret_cast<const int4*>(mbaseT + (size_t)kt * 16 * BN_);
                const int4 tw0 = tp[0];
                const int4 tw1 = tp[1];
                unsigned byT = (unsigned)(tw0.x != 0)        | ((unsigned)(tw0.y != 0) << 1)
                             | ((unsigned)(tw0.z != 0) << 2) | ((unsigned)(tw0.w != 0) << 3)
                             | ((unsigned)(tw1.x != 0) << 4) | ((unsigned)(tw1.y != 0) << 5)
                             | ((unsigned)(tw1.z != 0) << 6) | ((unsigned)(tw1.w != 0) << 7);
                pmBT[(kt * 16 + mr) * 16 + mc] = (unsigned char)byT;
            }
        }

        __syncthreads();   // LDS tiles ready (ebf staged + bit-tiles written)

#pragma unroll
        for (int ks = 0; ks < 2; ++ks) {
            bf16x8 af[4], bfr[4];
#pragma unroll
            for (int fm = 0; fm < 4; ++fm)
                af[fm] = *reinterpret_cast<const bf16x8*>(As + (wr * 64 + fm * 16 + r16) * 64 + ks * 32 + kg);
#pragma unroll
            for (int fn = 0; fn < 4; ++fn)
                bfr[fn] = *reinterpret_cast<const bf16x8*>(Bs + (wc * 64 + fn * 16 + r16) * 64 + ks * 32 + kg);
#pragma unroll
            for (int fm = 0; fm < 4; ++fm)
#pragma unroll
                for (int fn = 0; fn < 4; ++fn)
                    acc[fm][fn] = __builtin_amdgcn_mfma_f32_16x16x32_bf16(bfr[fn], af[fm], acc[fm][fn], 0, 0, 0);
        }
        __syncthreads();
    }

    // ---- epilogue ----
    const float C1 = TEMP_INV * LOG2E_;
    const float C2 = -MAXOFF * LOG2E_;
    const int l15 = lane & 15;
    const int g   = lane >> 4;
    const int gq4 = g * 4;

    // row mask words per fm (this wave's 64-col window selected by wc)
    uint2 rw[4];
#pragma unroll
    for (int fm = 0; fm < 4; ++fm) {
        const uint4 rv = *reinterpret_cast<const uint4*>(pmB + (wr * 64 + fm * 16 + l15) * 16);
        rw[fm].x = wc ? rv.z : rv.x;
        rw[fm].y = wc ? rv.w : rv.y;
    }
    float lseA[4] = {0.f, 0.f, 0.f, 0.f};
    float posA[4] = {0.f, 0.f, 0.f, 0.f};

#pragma unroll
    for (int fn = 0; fn < 4; ++fn) {
#pragma unroll
        for (int rg = 0; rg < 4; ++rg) {
            const int jl = wc * 64 + fn * 16 + gq4 + rg;   // local col / cb-row
            uint2 tv;
            if (offd) tv = *reinterpret_cast<const uint2*>(pmBT + jl * 16 + wr * 8);
            float colL = 0.f, colP = 0.f;
#pragma unroll
            for (int fm = 0; fm < 4; ++fm) {
                const float a = acc[fm][fn][rg];
                const bool dg = db && (wr == wc) && (fm == fn) && (l15 == gq4 + rg);
                const float ex = dg ? 0.0f : exp2f(fmaf(a, C1, C2));
                lseA[fm] += ex;
                const unsigned wsel = (fn < 2) ? rw[fm].x : rw[fm].y;
                const bool p = (((wsel >> ((fn & 1) * 16 + gq4 + rg)) & 1u) != 0u) && !dg;
                posA[fm] += p ? a : 0.0f;
                if (offd) {
                    colL += ex;   // symmetric credit: sim(j,i) == sim(i,j)
                    const unsigned cw = (fm < 2) ? tv.x : tv.y;
                    colP += ((cw >> ((fm & 1) * 16 + l15)) & 1u) ? a : 0.0f;
                }
            }
            if (offd) {
#pragma unroll
                for (int off = 1; off < 16; off <<= 1) {
                    colL += __shfl_xor(colL, off, 64);
                    colP += __shfl_xor(colP, off, 64);
                }
                if (l15 == 0) {
                    atomicAdd(&redC[0][jl], colL);
                    atomicAdd(&redC[1][jl], colP * TEMP_INV);
                }
            }
        }
    }
    // row-side: reduce over the 4 lane-groups (j spread over lane>>4)
#pragma unroll
    for (int fm = 0; fm < 4; ++fm) {
        float L = lseA[fm], P = posA[fm];
        L += __shfl_xor(L, 16, 64); L += __shfl_xor(L, 32, 64);
        P += __shfl_xor(P, 16, 64); P += __shfl_xor(P, 32, 64);
        if (g == 0) {
            const int li = wr * 64 + fm * 16 + l15;
            atomicAdd(&redR[0][li], L);
            atomicAdd(&redR[1][li], P * TEMP_INV);
        }
    }
    __syncthreads();
    if (t < 128) {
        const uint4 rv = *reinterpret_cast<const uint4*>(pmB + t * 16);
        float cnt = (float)(__popc(rv.x) + __popc(rv.y) + __popc(rv.z) + __popc(rv.w));
        if (db) {   // remove diagonal bit (diag col == local row t)
            const unsigned wsel = (t < 64) ? ((t < 32) ? rv.x : rv.y)
                                           : ((t < 96) ? rv.z : rv.w);
            cnt -= (float)((wsel >> (t & 31)) & 1u);
        }
        const int i = rb * 128 + t;
        atomicAdd(&se[i], redR[0][t]);
        atomicAdd(&ps[i], redR[1][t]);
        atomicAdd(&ct[i], cnt);
    } else if (offd) {
        const int r = t - 128;
        const uint4 tvr = *reinterpret_cast<const uint4*>(pmBT + r * 16);
        const float cnt = (float)(__popc(tvr.x) + __popc(tvr.y) + __popc(tvr.z) + __popc(tvr.w));
        const int j = cb * 128 + r;
        atomicAdd(&se[j], redC[0][r]);
        atomicAdd(&ps[j], redC[1][r]);
        atomicAdd(&ct[j], cnt);
    }
}

// ---------------- Kernel 3: finalize scalar loss (32 blocks) ----------------
__global__ __launch_bounds__(256) void finalize_kernel(const float* __restrict__ se,
                                                       const float* __restrict__ ps,
                                                       const float* __restrict__ ct,
                                                       float* __restrict__ out) {
    __shared__ float red[256];
    const int t = threadIdx.x;
    const int i = blockIdx.x * 256 + t;
    const float lse = logf(se[i]) + MAXOFF;
    red[t] = lse - ps[i] / fmaxf(ct[i], 1.0f);
    __syncthreads();
    for (int s = 128; s > 0; s >>= 1) {
        if (t < s) red[t] += red[t + s];
        __syncthreads();
    }
    if (t == 0) atomicAdd(out, red[0] * (1.0f / (float)BN_));
}

extern "C" void kernel_launch(void* const* d_in, const int* in_sizes, int n_in,
                              void* d_out, int out_size, void* d_ws, size_t ws_size,
                              hipStream_t stream) {
    const float* emb  = (const float*)d_in[0];
    const int*   mask = (const int*)d_in[1];
    float* out = (float*)d_out;

    char* ws = (char*)d_ws;
    unsigned short* ebf = (unsigned short*)ws;                  // 8 MB bf16 normalized
    float* se = (float*)(ws + (size_t)8 * 1024 * 1024);
    float* ps = se + BN_;
    float* ct = ps + BN_;

    hipMemsetAsync(se, 0, (size_t)3 * BN_ * sizeof(float), stream);
    hipMemsetAsync(out, 0, sizeof(float), stream);
    norm_kernel<<<BN_ / 4, 256, 0, stream>>>(emb, ebf);
    infonce_main<<<2080, 256, 0, stream>>>(ebf, mask, se, ps, ct);
    finalize_kernel<<<BN_ / 256, 256, 0, stream>>>(se, ps, ct, out);
}

// Round 9
// 157.852 us; speedup vs baseline: 1.4232x; 1.1616x over previous
//
#include <hip/hip_runtime.h>
#include <hip/hip_bf16.h>

// Problem constants (B=8192, D=512 from reference setup_inputs)
#define BN_ 8192
#define DK_ 512
#define TEMP_INV 14.2857142857142857f   // 1/0.07
#define LOG2E_ 1.44269504088896f
#define MAXOFF 15.0f                    // fixed lse offset; |sim| < 14.29 (unit vectors)

typedef __bf16 bf16x8 __attribute__((ext_vector_type(8)));
typedef float f32x4 __attribute__((ext_vector_type(4)));

__device__ inline unsigned short f2bf(float f) {
    unsigned u = __float_as_uint(f);
    return (unsigned short)((u + 0x7FFFu + ((u >> 16) & 1u)) >> 16);
}

// ---------------- Kernel 1: L2-normalize rows, write bf16 ----------------
__global__ __launch_bounds__(256) void norm_kernel(const float* __restrict__ emb,
                                                   unsigned short* __restrict__ ebf) {
    const int row  = blockIdx.x * 4 + (threadIdx.x >> 6);
    const int lane = threadIdx.x & 63;
    const float4* src = reinterpret_cast<const float4*>(emb + (size_t)row * DK_);
    float4 v0 = src[lane];
    float4 v1 = src[lane + 64];
    float ss = v0.x*v0.x + v0.y*v0.y + v0.z*v0.z + v0.w*v0.w
             + v1.x*v1.x + v1.y*v1.y + v1.z*v1.z + v1.w*v1.w;
#pragma unroll
    for (int off = 1; off < 64; off <<= 1) ss += __shfl_xor(ss, off, 64);
    const float scale = 1.0f / fmaxf(sqrtf(ss), 1e-12f);
    uint2 o0, o1;
    o0.x = (unsigned)f2bf(v0.x * scale) | ((unsigned)f2bf(v0.y * scale) << 16);
    o0.y = (unsigned)f2bf(v0.z * scale) | ((unsigned)f2bf(v0.w * scale) << 16);
    o1.x = (unsigned)f2bf(v1.x * scale) | ((unsigned)f2bf(v1.y * scale) << 16);
    o1.y = (unsigned)f2bf(v1.z * scale) | ((unsigned)f2bf(v1.w * scale) << 16);
    uint2* dst = reinterpret_cast<uint2*>(ebf + (size_t)row * DK_);
    dst[lane]      = o0;
    dst[lane + 64] = o1;
}

// ---------------- Kernel 2: r6 structure + counted-vmcnt double-buffer ----------------
// grid (64,64); 256 threads = 4 waves (wr,wc), each a 64x64 quadrant (16x16x32 frags).
// Pipeline per kt: {s_waitcnt vmcnt(2); s_barrier} -> pack mask(kt) -> issue
// stage(kt+1)+mask(kt+2) -> MFMA on buf[kt&1].  vmcnt(2) derivation: queue at
// kt-top = stage(kt)[8 loads] + mask(kt+1)[2 loads]; allowing the 2 newest
// completes stage(kt) and everything older (incl. mask(kt), issued 2 phases ago).
// Loads thus span barriers: stage gets ~1 compute phase, mask ~2 phases in flight.
// SWAPPED mfma operands (verified r5/r6): a = acc[fm][fn][rg] is sim(i,j) with
//   i = rb*128 + wr*64 + fm*16 + (lane&15)
//   j = cb*128 + wc*64 + fn*16 + (lane>>4)*4 + rg
__global__ __launch_bounds__(256, 2) void infonce_main(
    const unsigned short* __restrict__ ebf,
    const int* __restrict__ mask,
    float* __restrict__ se, float* __restrict__ ps, float* __restrict__ ct) {

    __shared__ unsigned short As[2][128 * 64];    // 2 x 16KB
    __shared__ unsigned short Bs[2][128 * 64];    // 2 x 16KB
    __shared__ unsigned char  pmB[128 * 16];      // 2KB mask bit-tile
    __shared__ float red2[2][128];                // 1KB row partials {lse, pos}

    const int t    = threadIdx.x;
    const int lane = t & 63;
    const int wid  = t >> 6;
    const int wr   = wid >> 1;
    const int wc   = wid & 1;
    const int rb   = blockIdx.x;
    const int cb   = blockIdx.y;

    if (t < 128) { red2[0][t] = 0.f; red2[1][t] = 0.f; }

    f32x4 acc[4][4] = {};

    // ebf staging map: thread t -> row t/8 (of 32), 16B chunk (t%8) within 64-elem k-row
    const int sr = t >> 3;
    const int sc = (t & 7) * 8;
    const size_t arow0 = (size_t)(rb * 128 + sr) * DK_ + sc;
    const size_t brow0 = (size_t)(cb * 128 + sr) * DK_ + sc;

    // mask staging map: thread t -> patch row t>>4 (of 16 per kt), cols (t&15)*8..+7
    const int mr = t >> 4;
    const int mc = t & 15;
    const int* mbase = mask + (size_t)(rb * 128 + mr) * BN_ + cb * 128 + mc * 8;

    const int r16 = lane & 15;
    const int kg  = (lane >> 4) * 8;

#define STAGE(buf, kt)                                                                     \
    {                                                                                      \
        const int k0_ = (kt) * 64;                                                         \
        _Pragma("unroll")                                                                  \
        for (int s = 0; s < 4; ++s) {                                                      \
            __builtin_amdgcn_global_load_lds(                                              \
                (const __attribute__((address_space(1))) void*)(ebf + arow0 + (size_t)s * 32 * DK_ + k0_), \
                (__attribute__((address_space(3))) void*)(&As[buf][0] + s * 2048 + t * 8), \
                16, 0, 0);                                                                 \
        }                                                                                  \
        _Pragma("unroll")                                                                  \
        for (int s = 0; s < 4; ++s) {                                                      \
            __builtin_amdgcn_global_load_lds(                                              \
                (const __attribute__((address_space(1))) void*)(ebf + brow0 + (size_t)s * 32 * DK_ + k0_), \
                (__attribute__((address_space(3))) void*)(&Bs[buf][0] + s * 2048 + t * 8), \
                16, 0, 0);                                                                 \
        }                                                                                  \
    }

    int4 m0[2], m1[2];   // 2-deep mask register pipeline (indices compile-time under unroll)

    // prologue, issue order matters for the vmcnt math: stage0 (8), mask0 (2), mask1 (2)
    STAGE(0, 0);
    asm volatile("" ::: "memory");
    { const int4* p = reinterpret_cast<const int4*>(mbase);                       m0[0] = p[0]; m1[0] = p[1]; }
    asm volatile("" ::: "memory");
    { const int4* p = reinterpret_cast<const int4*>(mbase + (size_t)16 * BN_);    m0[1] = p[0]; m1[1] = p[1]; }
    asm volatile("" ::: "memory");

#pragma unroll
    for (int kt = 0; kt < 8; ++kt) {
        if (kt < 7) { asm volatile("s_waitcnt vmcnt(2)" ::: "memory"); }
        else        { asm volatile("s_waitcnt vmcnt(0)" ::: "memory"); }
        __builtin_amdgcn_s_barrier();
        __builtin_amdgcn_sched_barrier(0);

        // pack mask(kt) (arrived: older than stage(kt) in the queue)
        {
            const int4 a = m0[kt & 1], b = m1[kt & 1];
            unsigned by = (unsigned)(a.x != 0)        | ((unsigned)(a.y != 0) << 1)
                        | ((unsigned)(a.z != 0) << 2) | ((unsigned)(a.w != 0) << 3)
                        | ((unsigned)(b.x != 0) << 4) | ((unsigned)(b.y != 0) << 5)
                        | ((unsigned)(b.z != 0) << 6) | ((unsigned)(b.w != 0) << 7);
            pmB[(kt * 16 + mr) * 16 + mc] = (unsigned char)by;
        }
        // issue next tile + next-next mask AFTER the barrier (dbuf write-safe)
        if (kt < 7) {
            STAGE((kt + 1) & 1, kt + 1);
            asm volatile("" ::: "memory");
            if (kt < 6) {
                const int4* p = reinterpret_cast<const int4*>(mbase + (size_t)(kt + 2) * 16 * BN_);
                m0[kt & 1] = p[0];
                m1[kt & 1] = p[1];
            }
            asm volatile("" ::: "memory");
        }
        __builtin_amdgcn_sched_barrier(0);

        const unsigned short* Ab = &As[kt & 1][0];
        const unsigned short* Bb = &Bs[kt & 1][0];
#pragma unroll
        for (int ks = 0; ks < 2; ++ks) {
            bf16x8 af[4], bfr[4];
#pragma unroll
            for (int fm = 0; fm < 4; ++fm)
                af[fm] = *reinterpret_cast<const bf16x8*>(Ab + (wr * 64 + fm * 16 + r16) * 64 + ks * 32 + kg);
#pragma unroll
            for (int fn = 0; fn < 4; ++fn)
                bfr[fn] = *reinterpret_cast<const bf16x8*>(Bb + (wc * 64 + fn * 16 + r16) * 64 + ks * 32 + kg);
#pragma unroll
            for (int fm = 0; fm < 4; ++fm)
#pragma unroll
                for (int fn = 0; fn < 4; ++fn)
                    acc[fm][fn] = __builtin_amdgcn_mfma_f32_16x16x32_bf16(bfr[fn], af[fm], acc[fm][fn], 0, 0, 0);
        }
    }
#undef STAGE
    __syncthreads();   // full drain once: pmB writes visible to all for the epilogue

    // ---- epilogue (r6 verbatim): swapped layout -> in-lane row sums ----
    const float C1 = TEMP_INV * LOG2E_;
    const float C2 = -MAXOFF * LOG2E_;
    const bool  db  = (rb == cb);
    const int   gq4 = (lane >> 4) * 4;

#pragma unroll
    for (int fm = 0; fm < 4; ++fm) {
        const int li = wr * 64 + fm * 16 + (lane & 15);
        const uint4 rv = *reinterpret_cast<const uint4*>(pmB + li * 16);
        const unsigned w0 = wc ? rv.z : rv.x;   // this wave's 64-col window, bits 0..31
        const unsigned w1 = wc ? rv.w : rv.y;   // bits 32..63
        float lsep = 0.f, posp = 0.f;
#pragma unroll
        for (int fn = 0; fn < 4; ++fn) {
            const unsigned wsel = (fn < 2) ? w0 : w1;
#pragma unroll
            for (int rg = 0; rg < 4; ++rg) {
                const float a = acc[fm][fn][rg];
                const bool dg = db && (wr == wc) && (fm == fn) && ((lane & 15) == gq4 + rg);
                const float ex = dg ? 0.0f : exp2f(fmaf(a, C1, C2));
                lsep += ex;
                const bool p = (((wsel >> ((fn & 1) * 16 + gq4 + rg)) & 1u) != 0u) && !dg;
                posp += p ? a : 0.0f;
            }
        }
        lsep += __shfl_xor(lsep, 16, 64); lsep += __shfl_xor(lsep, 32, 64);
        posp += __shfl_xor(posp, 16, 64); posp += __shfl_xor(posp, 32, 64);
        if ((lane >> 4) == 0) {
            atomicAdd(&red2[0][li], lsep);                 // ds atomic, cross-wc merge
            atomicAdd(&red2[1][li], posp * TEMP_INV);
        }
    }
    __syncthreads();
    if (t < 128) {
        const uint4 rv = *reinterpret_cast<const uint4*>(pmB + t * 16);
        float cnt = (float)(__popc(rv.x) + __popc(rv.y) + __popc(rv.z) + __popc(rv.w));
        if (db) {   // remove diagonal bit from count (diag col == local row t)
            const unsigned wsel = (t < 64) ? ((t < 32) ? rv.x : rv.y)
                                           : ((t < 96) ? rv.z : rv.w);
            cnt -= (float)((wsel >> (t & 31)) & 1u);
        }
        const int i = rb * 128 + t;
        atomicAdd(&se[i], red2[0][t]);
        atomicAdd(&ps[i], red2[1][t]);
        atomicAdd(&ct[i], cnt);
    }
}

// ---------------- Kernel 3: finalize scalar loss (32 blocks) ----------------
__global__ __launch_bounds__(256) void finalize_kernel(const float* __restrict__ se,
                                                       const float* __restrict__ ps,
                                                       const float* __restrict__ ct,
                                                       float* __restrict__ out) {
    __shared__ float red[256];
    const int t = threadIdx.x;
    const int i = blockIdx.x * 256 + t;
    const float lse = logf(se[i]) + MAXOFF;
    red[t] = lse - ps[i] / fmaxf(ct[i], 1.0f);
    __syncthreads();
    for (int s = 128; s > 0; s >>= 1) {
        if (t < s) red[t] += red[t + s];
        __syncthreads();
    }
    if (t == 0) atomicAdd(out, red[0] * (1.0f / (float)BN_));
}

extern "C" void kernel_launch(void* const* d_in, const int* in_sizes, int n_in,
                              void* d_out, int out_size, void* d_ws, size_t ws_size,
                              hipStream_t stream) {
    const float* emb  = (const float*)d_in[0];
    const int*   mask = (const int*)d_in[1];
    float* out = (float*)d_out;

    char* ws = (char*)d_ws;
    unsigned short* ebf = (unsigned short*)ws;                  // 8 MB bf16 normalized
    float* se = (float*)(ws + (size_t)8 * 1024 * 1024);
    float* ps = se + BN_;
    float* ct = ps + BN_;

    hipMemsetAsync(se, 0, (size_t)3 * BN_ * sizeof(float), stream);
    hipMemsetAsync(out, 0, sizeof(float), stream);
    norm_kernel<<<BN_ / 4, 256, 0, stream>>>(emb, ebf);
    infonce_main<<<dim3(64, 64), 256, 0, stream>>>(ebf, mask, se, ps, ct);
    finalize_kernel<<<BN_ / 256, 256, 0, stream>>>(se, ps, ct, out);
}

// Round 10
// 136.060 us; speedup vs baseline: 1.6511x; 1.1602x over previous
//
#include <hip/hip_runtime.h>
#include <hip/hip_bf16.h>

// Problem constants (B=8192, D=512 from reference setup_inputs)
#define BN_ 8192
#define DK_ 512
#define TEMP_INV 14.2857142857142857f   // 1/0.07
#define LOG2E_ 1.44269504088896f
#define MAXOFF 15.0f                    // fixed lse offset; |sim| < 14.29 (unit vectors)

typedef __bf16 bf16x8 __attribute__((ext_vector_type(8)));
typedef float f32x4 __attribute__((ext_vector_type(4)));

__device__ inline unsigned short f2bf(float f) {
    unsigned u = __float_as_uint(f);
    return (unsigned short)((u + 0x7FFFu + ((u >> 16) & 1u)) >> 16);
}

// ---------------- Kernel 1: L2-normalize rows, write bf16 ----------------
__global__ __launch_bounds__(256) void norm_kernel(const float* __restrict__ emb,
                                                   unsigned short* __restrict__ ebf) {
    const int row  = blockIdx.x * 4 + (threadIdx.x >> 6);
    const int lane = threadIdx.x & 63;
    const float4* src = reinterpret_cast<const float4*>(emb + (size_t)row * DK_);
    float4 v0 = src[lane];
    float4 v1 = src[lane + 64];
    float ss = v0.x*v0.x + v0.y*v0.y + v0.z*v0.z + v0.w*v0.w
             + v1.x*v1.x + v1.y*v1.y + v1.z*v1.z + v1.w*v1.w;
#pragma unroll
    for (int off = 1; off < 64; off <<= 1) ss += __shfl_xor(ss, off, 64);
    const float scale = 1.0f / fmaxf(sqrtf(ss), 1e-12f);
    uint2 o0, o1;
    o0.x = (unsigned)f2bf(v0.x * scale) | ((unsigned)f2bf(v0.y * scale) << 16);
    o0.y = (unsigned)f2bf(v0.z * scale) | ((unsigned)f2bf(v0.w * scale) << 16);
    o1.x = (unsigned)f2bf(v1.x * scale) | ((unsigned)f2bf(v1.y * scale) << 16);
    o1.y = (unsigned)f2bf(v1.z * scale) | ((unsigned)f2bf(v1.w * scale) << 16);
    uint2* dst = reinterpret_cast<uint2*>(ebf + (size_t)row * DK_);
    dst[lane]      = o0;
    dst[lane + 64] = o1;
}

// ---------------- Kernel 2: r6 geometry + register-pipelined mask ----------------
// grid (64,64); 256 threads = 4 waves (wr,wc), each a 64x64 quadrant (16x16x32 frags).
// SINGLE-buffer LDS (35KB -> 4 blocks/CU, the TLP this kernel lives on).  Only the
// mask is pipelined: mask(kt+1) issued with STAGE(kt), held in regs; the top barrier
// uses counted s_waitcnt vmcnt(2) so the 2 newest loads (mask(kt+1)) stay in flight
// across it and hide under the MFMA phase.  Queue at the wait (kt in 1..6):
//   [mask(kt), stage(kt)(8), mask(kt+1)(2)] -> vmcnt(2) completes mask(kt)+stage(kt).
// Second barrier (raw, no vm-wait) after MFMA protects the single buffer.
// SWAPPED mfma operands (verified r5/r6): a = acc[fm][fn][rg] is sim(i,j) with
//   i = rb*128 + wr*64 + fm*16 + (lane&15)
//   j = cb*128 + wc*64 + fn*16 + (lane>>4)*4 + rg
__global__ __launch_bounds__(256, 4) void infonce_main(
    const unsigned short* __restrict__ ebf,
    const int* __restrict__ mask,
    float* __restrict__ se, float* __restrict__ ps, float* __restrict__ ct) {

    __shared__ unsigned short As[128 * 64];       // 16KB
    __shared__ unsigned short Bs[128 * 64];       // 16KB
    __shared__ unsigned char  pmB[128 * 16];      // 2KB mask bit-tile
    __shared__ float red2[2][128];                // 1KB row partials {lse, pos}

    const int t    = threadIdx.x;
    const int lane = t & 63;
    const int wid  = t >> 6;
    const int wr   = wid >> 1;
    const int wc   = wid & 1;
    const int rb   = blockIdx.x;
    const int cb   = blockIdx.y;

    if (t < 128) { red2[0][t] = 0.f; red2[1][t] = 0.f; }

    f32x4 acc[4][4] = {};

    // ebf staging map: thread t -> row t/8 (of 32), 16B chunk (t%8) within 64-elem k-row
    const int sr = t >> 3;
    const int sc = (t & 7) * 8;
    const size_t arow0 = (size_t)(rb * 128 + sr) * DK_ + sc;
    const size_t brow0 = (size_t)(cb * 128 + sr) * DK_ + sc;

    // mask staging map: thread t -> patch row t>>4 (of 16 per kt), cols (t&15)*8..+7
    const int mr = t >> 4;
    const int mc = t & 15;
    const int* mbase = mask + (size_t)(rb * 128 + mr) * BN_ + cb * 128 + mc * 8;

    const int r16 = lane & 15;
    const int kg  = (lane >> 4) * 8;

#define STAGE(kt)                                                                          \
    {                                                                                      \
        const int k0_ = (kt) * 64;                                                         \
        _Pragma("unroll")                                                                  \
        for (int s = 0; s < 4; ++s) {                                                      \
            __builtin_amdgcn_global_load_lds(                                              \
                (const __attribute__((address_space(1))) void*)(ebf + arow0 + (size_t)s * 32 * DK_ + k0_), \
                (__attribute__((address_space(3))) void*)(As + s * 2048 + t * 8),          \
                16, 0, 0);                                                                 \
        }                                                                                  \
        _Pragma("unroll")                                                                  \
        for (int s = 0; s < 4; ++s) {                                                      \
            __builtin_amdgcn_global_load_lds(                                              \
                (const __attribute__((address_space(1))) void*)(ebf + brow0 + (size_t)s * 32 * DK_ + k0_), \
                (__attribute__((address_space(3))) void*)(Bs + s * 2048 + t * 8),          \
                16, 0, 0);                                                                 \
        }                                                                                  \
    }

    int4 m0[2], m1[2];   // 1-phase-deep mask register pipeline (static idx under unroll)

    // prologue: mask(0) in flight before the loop (oldest in queue)
    { const int4* p = reinterpret_cast<const int4*>(mbase); m0[0] = p[0]; m1[0] = p[1]; }
    asm volatile("" ::: "memory");

#pragma unroll
    for (int kt = 0; kt < 8; ++kt) {
        STAGE(kt);
        asm volatile("" ::: "memory");
        if (kt < 7) {   // issue mask(kt+1): the 2 newest vmcnt ops at the wait below
            const int4* p = reinterpret_cast<const int4*>(mbase + (size_t)(kt + 1) * 16 * BN_);
            m0[(kt + 1) & 1] = p[0];
            m1[(kt + 1) & 1] = p[1];
        }
        asm volatile("" ::: "memory");
        if (kt < 7) { asm volatile("s_waitcnt vmcnt(2)" ::: "memory"); }
        else        { asm volatile("s_waitcnt vmcnt(0)" ::: "memory"); }
        __builtin_amdgcn_s_barrier();            // top barrier: stage(kt)+mask(kt) ready
        __builtin_amdgcn_sched_barrier(0);

        // pack mask(kt) (complete: older than stage(kt) at the wait)
        {
            const int4 a = m0[kt & 1], b = m1[kt & 1];
            unsigned by = (unsigned)(a.x != 0)        | ((unsigned)(a.y != 0) << 1)
                        | ((unsigned)(a.z != 0) << 2) | ((unsigned)(a.w != 0) << 3)
                        | ((unsigned)(b.x != 0) << 4) | ((unsigned)(b.y != 0) << 5)
                        | ((unsigned)(b.z != 0) << 6) | ((unsigned)(b.w != 0) << 7);
            pmB[(kt * 16 + mr) * 16 + mc] = (unsigned char)by;
        }

#pragma unroll
        for (int ks = 0; ks < 2; ++ks) {
            bf16x8 af[4], bfr[4];
#pragma unroll
            for (int fm = 0; fm < 4; ++fm)
                af[fm] = *reinterpret_cast<const bf16x8*>(As + (wr * 64 + fm * 16 + r16) * 64 + ks * 32 + kg);
#pragma unroll
            for (int fn = 0; fn < 4; ++fn)
                bfr[fn] = *reinterpret_cast<const bf16x8*>(Bs + (wc * 64 + fn * 16 + r16) * 64 + ks * 32 + kg);
#pragma unroll
            for (int fm = 0; fm < 4; ++fm)
#pragma unroll
                for (int fn = 0; fn < 4; ++fn)
                    acc[fm][fn] = __builtin_amdgcn_mfma_f32_16x16x32_bf16(bfr[fn], af[fm], acc[fm][fn], 0, 0, 0);
        }
        __builtin_amdgcn_sched_barrier(0);
        __builtin_amdgcn_s_barrier();            // bottom barrier: buf reads done, no vm drain
        __builtin_amdgcn_sched_barrier(0);
    }
#undef STAGE
    __syncthreads();   // full drain once: pmB writes visible for the epilogue

    // ---- epilogue (r6 verbatim): swapped layout -> in-lane row sums ----
    const float C1 = TEMP_INV * LOG2E_;
    const float C2 = -MAXOFF * LOG2E_;
    const bool  db  = (rb == cb);
    const int   gq4 = (lane >> 4) * 4;

#pragma unroll
    for (int fm = 0; fm < 4; ++fm) {
        const int li = wr * 64 + fm * 16 + (lane & 15);
        const uint4 rv = *reinterpret_cast<const uint4*>(pmB + li * 16);
        const unsigned w0 = wc ? rv.z : rv.x;   // this wave's 64-col window, bits 0..31
        const unsigned w1 = wc ? rv.w : rv.y;   // bits 32..63
        float lsep = 0.f, posp = 0.f;
#pragma unroll
        for (int fn = 0; fn < 4; ++fn) {
            const unsigned wsel = (fn < 2) ? w0 : w1;
#pragma unroll
            for (int rg = 0; rg < 4; ++rg) {
                const float a = acc[fm][fn][rg];
                const bool dg = db && (wr == wc) && (fm == fn) && ((lane & 15) == gq4 + rg);
                const float ex = dg ? 0.0f : exp2f(fmaf(a, C1, C2));
                lsep += ex;
                const bool p = (((wsel >> ((fn & 1) * 16 + gq4 + rg)) & 1u) != 0u) && !dg;
                posp += p ? a : 0.0f;
            }
        }
        lsep += __shfl_xor(lsep, 16, 64); lsep += __shfl_xor(lsep, 32, 64);
        posp += __shfl_xor(posp, 16, 64); posp += __shfl_xor(posp, 32, 64);
        if ((lane >> 4) == 0) {
            atomicAdd(&red2[0][li], lsep);                 // ds atomic, cross-wc merge
            atomicAdd(&red2[1][li], posp * TEMP_INV);
        }
    }
    __syncthreads();
    if (t < 128) {
        const uint4 rv = *reinterpret_cast<const uint4*>(pmB + t * 16);
        float cnt = (float)(__popc(rv.x) + __popc(rv.y) + __popc(rv.z) + __popc(rv.w));
        if (db) {   // remove diagonal bit from count (diag col == local row t)
            const unsigned wsel = (t < 64) ? ((t < 32) ? rv.x : rv.y)
                                           : ((t < 96) ? rv.z : rv.w);
            cnt -= (float)((wsel >> (t & 31)) & 1u);
        }
        const int i = rb * 128 + t;
        atomicAdd(&se[i], red2[0][t]);
        atomicAdd(&ps[i], red2[1][t]);
        atomicAdd(&ct[i], cnt);
    }
}

// ---------------- Kernel 3: finalize scalar loss (32 blocks) ----------------
__global__ __launch_bounds__(256) void finalize_kernel(const float* __restrict__ se,
                                                       const float* __restrict__ ps,
                                                       const float* __restrict__ ct,
                                                       float* __restrict__ out) {
    __shared__ float red[256];
    const int t = threadIdx.x;
    const int i = blockIdx.x * 256 + t;
    const float lse = logf(se[i]) + MAXOFF;
    red[t] = lse - ps[i] / fmaxf(ct[i], 1.0f);
    __syncthreads();
    for (int s = 128; s > 0; s >>= 1) {
        if (t < s) red[t] += red[t + s];
        __syncthreads();
    }
    if (t == 0) atomicAdd(out, red[0] * (1.0f / (float)BN_));
}

extern "C" void kernel_launch(void* const* d_in, const int* in_sizes, int n_in,
                              void* d_out, int out_size, void* d_ws, size_t ws_size,
                              hipStream_t stream) {
    const float* emb  = (const float*)d_in[0];
    const int*   mask = (const int*)d_in[1];
    float* out = (float*)d_out;

    char* ws = (char*)d_ws;
    unsigned short* ebf = (unsigned short*)ws;                  // 8 MB bf16 normalized
    float* se = (float*)(ws + (size_t)8 * 1024 * 1024);
    float* ps = se + BN_;
    float* ct = ps + BN_;

    hipMemsetAsync(se, 0, (size_t)3 * BN_ * sizeof(float), stream);
    hipMemsetAsync(out, 0, sizeof(float), stream);
    norm_kernel<<<BN_ / 4, 256, 0, stream>>>(emb, ebf);
    infonce_main<<<dim3(64, 64), 256, 0, stream>>>(ebf, mask, se, ps, ct);
    finalize_kernel<<<BN_ / 256, 256, 0, stream>>>(se, ps, ct, out);
}

// Round 11
// 116.516 us; speedup vs baseline: 1.9281x; 1.1677x over previous
//
#include <hip/hip_runtime.h>
#include <hip/hip_bf16.h>

// Problem constants (B=8192, D=512 from reference setup_inputs)
#define BN_ 8192
#define DK_ 512
#define TEMP_INV 14.2857142857142857f   // 1/0.07
#define LOG2E_ 1.44269504088896f
#define MAXOFF 15.0f                    // fixed lse offset; |sim| < 14.29 (unit vectors)

typedef __bf16 bf16x8 __attribute__((ext_vector_type(8)));
typedef float f32x4 __attribute__((ext_vector_type(4)));

__device__ inline unsigned short f2bf(float f) {
    unsigned u = __float_as_uint(f);
    return (unsigned short)((u + 0x7FFFu + ((u >> 16) & 1u)) >> 16);
}

// ---------------- Kernel 1: L2-normalize rows, write bf16 ----------------
__global__ __launch_bounds__(256) void norm_kernel(const float* __restrict__ emb,
                                                   unsigned short* __restrict__ ebf) {
    const int row  = blockIdx.x * 4 + (threadIdx.x >> 6);
    const int lane = threadIdx.x & 63;
    const float4* src = reinterpret_cast<const float4*>(emb + (size_t)row * DK_);
    float4 v0 = src[lane];
    float4 v1 = src[lane + 64];
    float ss = v0.x*v0.x + v0.y*v0.y + v0.z*v0.z + v0.w*v0.w
             + v1.x*v1.x + v1.y*v1.y + v1.z*v1.z + v1.w*v1.w;
#pragma unroll
    for (int off = 1; off < 64; off <<= 1) ss += __shfl_xor(ss, off, 64);
    const float scale = 1.0f / fmaxf(sqrtf(ss), 1e-12f);
    uint2 o0, o1;
    o0.x = (unsigned)f2bf(v0.x * scale) | ((unsigned)f2bf(v0.y * scale) << 16);
    o0.y = (unsigned)f2bf(v0.z * scale) | ((unsigned)f2bf(v0.w * scale) << 16);
    o1.x = (unsigned)f2bf(v1.x * scale) | ((unsigned)f2bf(v1.y * scale) << 16);
    o1.y = (unsigned)f2bf(v1.z * scale) | ((unsigned)f2bf(v1.w * scale) << 16);
    uint2* dst = reinterpret_cast<uint2*>(ebf + (size_t)row * DK_);
    dst[lane]      = o0;
    dst[lane + 64] = o1;
}

// ---------------- Kernel 2: r10 + T2 both-sides XOR swizzle ----------------
// grid (64,64); 256 threads = 4 waves (wr,wc), each a 64x64 quadrant (16x16x32 frags).
// SINGLE change vs r10: the [128][64] bf16 LDS tiles (128B row stride) gave a 16-way
// bank conflict on every ds_read_b128 (SQ_LDS_BANK_CONFLICT=2.5e7 ~= 98k cy/CU, the
// measured bottleneck).  Fix per rule 21: LDS dest stays LINEAR (global_load_lds
// requirement); the global SOURCE chunk is pre-swizzled  sc = ((t&7)^((t>>3)&7))*8
// so LDS chunk c of row r holds global chunk c^(r&7); reads fetch chunk
// ((ks*4 + lane>>4) ^ (r16&7)) -> 8 lanes/chunk, uniform 8 words/bank, conflict-free.
// SWAPPED mfma operands (verified r5/r6): a = acc[fm][fn][rg] is sim(i,j) with
//   i = rb*128 + wr*64 + fm*16 + (lane&15)
//   j = cb*128 + wc*64 + fn*16 + (lane>>4)*4 + rg
__global__ __launch_bounds__(256, 4) void infonce_main(
    const unsigned short* __restrict__ ebf,
    const int* __restrict__ mask,
    float* __restrict__ se, float* __restrict__ ps, float* __restrict__ ct) {

    __shared__ unsigned short As[128 * 64];       // 16KB
    __shared__ unsigned short Bs[128 * 64];       // 16KB
    __shared__ unsigned char  pmB[128 * 16];      // 2KB mask bit-tile
    __shared__ float red2[2][128];                // 1KB row partials {lse, pos}

    const int t    = threadIdx.x;
    const int lane = t & 63;
    const int wid  = t >> 6;
    const int wr   = wid >> 1;
    const int wc   = wid & 1;
    const int rb   = blockIdx.x;
    const int cb   = blockIdx.y;

    if (t < 128) { red2[0][t] = 0.f; red2[1][t] = 0.f; }

    f32x4 acc[4][4] = {};

    // ebf staging map: thread t -> row t/8 (of 32 per slab); global source chunk is
    // PRE-SWIZZLED so the linear LDS write lands global chunk c^(row&7) at chunk c.
    const int sr  = t >> 3;
    const int scs = (((t & 7) ^ (sr & 7)) * 8);
    const size_t arow0 = (size_t)(rb * 128 + sr) * DK_ + scs;
    const size_t brow0 = (size_t)(cb * 128 + sr) * DK_ + scs;

    // mask staging map: thread t -> patch row t>>4 (of 16 per kt), cols (t&15)*8..+7
    const int mr = t >> 4;
    const int mc = t & 15;
    const int* mbase = mask + (size_t)(rb * 128 + mr) * BN_ + cb * 128 + mc * 8;

    const int r16 = lane & 15;
    const int g4  = lane >> 4;
    const int r7  = r16 & 7;

#define STAGE(kt)                                                                          \
    {                                                                                      \
        const int k0_ = (kt) * 64;                                                         \
        _Pragma("unroll")                                                                  \
        for (int s = 0; s < 4; ++s) {                                                      \
            __builtin_amdgcn_global_load_lds(                                              \
                (const __attribute__((address_space(1))) void*)(ebf + arow0 + (size_t)s * 32 * DK_ + k0_), \
                (__attribute__((address_space(3))) void*)(As + s * 2048 + t * 8),          \
                16, 0, 0);                                                                 \
        }                                                                                  \
        _Pragma("unroll")                                                                  \
        for (int s = 0; s < 4; ++s) {                                                      \
            __builtin_amdgcn_global_load_lds(                                              \
                (const __attribute__((address_space(1))) void*)(ebf + brow0 + (size_t)s * 32 * DK_ + k0_), \
                (__attribute__((address_space(3))) void*)(Bs + s * 2048 + t * 8),          \
                16, 0, 0);                                                                 \
        }                                                                                  \
    }

    int4 m0[2], m1[2];   // 1-phase-deep mask register pipeline (static idx under unroll)

    // prologue: mask(0) in flight before the loop (oldest in queue)
    { const int4* p = reinterpret_cast<const int4*>(mbase); m0[0] = p[0]; m1[0] = p[1]; }
    asm volatile("" ::: "memory");

#pragma unroll
    for (int kt = 0; kt < 8; ++kt) {
        STAGE(kt);
        asm volatile("" ::: "memory");
        if (kt < 7) {   // issue mask(kt+1): the 2 newest vmcnt ops at the wait below
            const int4* p = reinterpret_cast<const int4*>(mbase + (size_t)(kt + 1) * 16 * BN_);
            m0[(kt + 1) & 1] = p[0];
            m1[(kt + 1) & 1] = p[1];
        }
        asm volatile("" ::: "memory");
        if (kt < 7) { asm volatile("s_waitcnt vmcnt(2)" ::: "memory"); }
        else        { asm volatile("s_waitcnt vmcnt(0)" ::: "memory"); }
        __builtin_amdgcn_s_barrier();            // top barrier: stage(kt)+mask(kt) ready
        __builtin_amdgcn_sched_barrier(0);

        // pack mask(kt) (complete: older than stage(kt) at the wait)
        {
            const int4 a = m0[kt & 1], b = m1[kt & 1];
            unsigned by = (unsigned)(a.x != 0)        | ((unsigned)(a.y != 0) << 1)
                        | ((unsigned)(a.z != 0) << 2) | ((unsigned)(a.w != 0) << 3)
                        | ((unsigned)(b.x != 0) << 4) | ((unsigned)(b.y != 0) << 5)
                        | ((unsigned)(b.z != 0) << 6) | ((unsigned)(b.w != 0) << 7);
            pmB[(kt * 16 + mr) * 16 + mc] = (unsigned char)by;
        }

#pragma unroll
        for (int ks = 0; ks < 2; ++ks) {
            bf16x8 af[4], bfr[4];
            const int koff = (((ks * 4 + g4) ^ r7) * 8);   // swizzled chunk within row
#pragma unroll
            for (int fm = 0; fm < 4; ++fm)
                af[fm] = *reinterpret_cast<const bf16x8*>(As + (wr * 64 + fm * 16 + r16) * 64 + koff);
#pragma unroll
            for (int fn = 0; fn < 4; ++fn)
                bfr[fn] = *reinterpret_cast<const bf16x8*>(Bs + (wc * 64 + fn * 16 + r16) * 64 + koff);
#pragma unroll
            for (int fm = 0; fm < 4; ++fm)
#pragma unroll
                for (int fn = 0; fn < 4; ++fn)
                    acc[fm][fn] = __builtin_amdgcn_mfma_f32_16x16x32_bf16(bfr[fn], af[fm], acc[fm][fn], 0, 0, 0);
        }
        __builtin_amdgcn_sched_barrier(0);
        __builtin_amdgcn_s_barrier();            // bottom barrier: buf reads done, no vm drain
        __builtin_amdgcn_sched_barrier(0);
    }
#undef STAGE
    __syncthreads();   // full drain once: pmB writes visible for the epilogue

    // ---- epilogue (r6 verbatim): swapped layout -> in-lane row sums ----
    const float C1 = TEMP_INV * LOG2E_;
    const float C2 = -MAXOFF * LOG2E_;
    const bool  db  = (rb == cb);
    const int   gq4 = (lane >> 4) * 4;

#pragma unroll
    for (int fm = 0; fm < 4; ++fm) {
        const int li = wr * 64 + fm * 16 + (lane & 15);
        const uint4 rv = *reinterpret_cast<const uint4*>(pmB + li * 16);
        const unsigned w0 = wc ? rv.z : rv.x;   // this wave's 64-col window, bits 0..31
        const unsigned w1 = wc ? rv.w : rv.y;   // bits 32..63
        float lsep = 0.f, posp = 0.f;
#pragma unroll
        for (int fn = 0; fn < 4; ++fn) {
            const unsigned wsel = (fn < 2) ? w0 : w1;
#pragma unroll
            for (int rg = 0; rg < 4; ++rg) {
                const float a = acc[fm][fn][rg];
                const bool dg = db && (wr == wc) && (fm == fn) && ((lane & 15) == gq4 + rg);
                const float ex = dg ? 0.0f : exp2f(fmaf(a, C1, C2));
                lsep += ex;
                const bool p = (((wsel >> ((fn & 1) * 16 + gq4 + rg)) & 1u) != 0u) && !dg;
                posp += p ? a : 0.0f;
            }
        }
        lsep += __shfl_xor(lsep, 16, 64); lsep += __shfl_xor(lsep, 32, 64);
        posp += __shfl_xor(posp, 16, 64); posp += __shfl_xor(posp, 32, 64);
        if ((lane >> 4) == 0) {
            atomicAdd(&red2[0][li], lsep);                 // ds atomic, cross-wc merge
            atomicAdd(&red2[1][li], posp * TEMP_INV);
        }
    }
    __syncthreads();
    if (t < 128) {
        const uint4 rv = *reinterpret_cast<const uint4*>(pmB + t * 16);
        float cnt = (float)(__popc(rv.x) + __popc(rv.y) + __popc(rv.z) + __popc(rv.w));
        if (db) {   // remove diagonal bit from count (diag col == local row t)
            const unsigned wsel = (t < 64) ? ((t < 32) ? rv.x : rv.y)
                                           : ((t < 96) ? rv.z : rv.w);
            cnt -= (float)((wsel >> (t & 31)) & 1u);
        }
        const int i = rb * 128 + t;
        atomicAdd(&se[i], red2[0][t]);
        atomicAdd(&ps[i], red2[1][t]);
        atomicAdd(&ct[i], cnt);
    }
}

// ---------------- Kernel 3: finalize scalar loss (32 blocks) ----------------
__global__ __launch_bounds__(256) void finalize_kernel(const float* __restrict__ se,
                                                       const float* __restrict__ ps,
                                                       const float* __restrict__ ct,
                                                       float* __restrict__ out) {
    __shared__ float red[256];
    const int t = threadIdx.x;
    const int i = blockIdx.x * 256 + t;
    const float lse = logf(se[i]) + MAXOFF;
    red[t] = lse - ps[i] / fmaxf(ct[i], 1.0f);
    __syncthreads();
    for (int s = 128; s > 0; s >>= 1) {
        if (t < s) red[t] += red[t + s];
        __syncthreads();
    }
    if (t == 0) atomicAdd(out, red[0] * (1.0f / (float)BN_));
}

extern "C" void kernel_launch(void* const* d_in, const int* in_sizes, int n_in,
                              void* d_out, int out_size, void* d_ws, size_t ws_size,
                              hipStream_t stream) {
    const float* emb  = (const float*)d_in[0];
    const int*   mask = (const int*)d_in[1];
    float* out = (float*)d_out;

    char* ws = (char*)d_ws;
    unsigned short* ebf = (unsigned short*)ws;                  // 8 MB bf16 normalized
    float* se = (float*)(ws + (size_t)8 * 1024 * 1024);
    float* ps = se + BN_;
    float* ct = ps + BN_;

    hipMemsetAsync(se, 0, (size_t)3 * BN_ * sizeof(float), stream);
    hipMemsetAsync(out, 0, sizeof(float), stream);
    norm_kernel<<<BN_ / 4, 256, 0, stream>>>(emb, ebf);
    infonce_main<<<dim3(64, 64), 256, 0, stream>>>(ebf, mask, se, ps, ct);
    finalize_kernel<<<BN_ / 256, 256, 0, stream>>>(se, ps, ct, out);
}